// Round 3
// baseline (77.701 us; speedup 1.0000x reference)
//
#include <hip/hip_runtime.h>
#include <math.h>

#define IN_CH 4
#define KSZ 3
#define NUM_KERNELS 2
#define NPOS 9          // KSZ*KSZ
#define HH 64
#define WW 64
#define BB 16
#define OH 62
#define OW 62
#define NPATCH (BB*OH*OW)   // 61504
#define NU (NPOS*IN_CH)     // 36 unitaries per kernel
#define UFLOATS (NU*8)      // 288 floats per kernel

// ---------------------------------------------------------------------------
// Precompute the fused per-(kernel,pos,qubit) unitary  U = Rz(t2)*Ry(t1)*Rx(t0)
// 72 threads total. Written to workspace as [k][pos][q][8] floats
// (u00r,u00i,u01r,u01i,u10r,u10i,u11r,u11i).
// ---------------------------------------------------------------------------
__global__ void qk_precompute(const float* __restrict__ w, float* __restrict__ U) {
    int t = blockIdx.x * blockDim.x + threadIdx.x;
    if (t >= NUM_KERNELS * NU) return;
    int k   = t / NU;
    int rem = t % NU;          // pos*IN_CH + q
    const float* wp = w + k * (NU * 3) + rem * 3;   // w.reshape(NPOS,1,IN_CH,3)
    float hx = 0.5f * wp[0], hy = 0.5f * wp[1], hz = 0.5f * wp[2];
    float cx = cosf(hx), sx = sinf(hx);
    float cy = cosf(hy), sy = sinf(hy);
    float cz = cosf(hz), sz = sinf(hz);
    // M = Ry * Rx   (Rx = [[cx, -i sx],[-i sx, cx]], Ry = [[cy,-sy],[sy,cy]])
    float m00r =  cy * cx, m00i =  sy * sx;
    float m01r = -sy * cx, m01i = -cy * sx;
    float m10r =  sy * cx, m10i = -cy * sx;
    float m11r =  cy * cx, m11i = -sy * sx;
    // U = Rz * M   (row0 *= cz - i sz ; row1 *= cz + i sz)
    float* o = U + t * 8;
    o[0] = cz * m00r + sz * m00i;  o[1] = cz * m00i - sz * m00r;
    o[2] = cz * m01r + sz * m01i;  o[3] = cz * m01i - sz * m01r;
    o[4] = cz * m10r - sz * m10i;  o[5] = cz * m10i + sz * m10r;
    o[6] = cz * m11r - sz * m11i;  o[7] = cz * m11i + sz * m11r;
}

// ---------------------------------------------------------------------------
// Main kernel: one thread per (patch, kernel). State = 16 complex amplitudes
// in registers (qubit q bit = 8>>q, C-order flatten of (2,2,2,2)).
// ---------------------------------------------------------------------------
__global__ __launch_bounds__(256) void qk_main(const float* __restrict__ x,
                                               const float* __restrict__ Uglob,
                                               float* __restrict__ out) {
    __shared__ float sU[UFLOATS];
    const int kidx = blockIdx.y;
    const int tid  = threadIdx.x;
    // UFLOATS (288) > blockDim (256): must stride the fill. (Round-1 bug:
    // `if (tid < UFLOATS)` left sU[256..287] = pos-8's unitaries garbage.)
    for (int t = tid; t < UFLOATS; t += 256) sU[t] = Uglob[kidx * UFLOATS + t];
    __syncthreads();

    int p = blockIdx.x * 256 + tid;
    if (p >= NPATCH) return;
    int b   = p / (OH * OW);
    int rem = p - b * (OH * OW);
    int oh  = rem / OW;
    int ow  = rem - oh * OW;
    const float* xb = x + b * (IN_CH * HH * WW);

    float sr[16], si[16];
    #pragma unroll
    for (int i = 0; i < 16; ++i) { sr[i] = 0.25f; si[i] = 0.0f; }  // H^⊗4 |0>

    #pragma unroll
    for (int kh = 0; kh < KSZ; ++kh) {
        #pragma unroll
        for (int kw = 0; kw < KSZ; ++kw) {
            const int pos = kh * KSZ + kw;
            // ---- data re-upload: RY(x[b,ch,oh+kh,ow+kw]) on qubit ch ----
            #pragma unroll
            for (int ch = 0; ch < IN_CH; ++ch) {
                float th = xb[ch * (HH * WW) + (oh + kh) * WW + (ow + kw)];
                float s, c;
                __sincosf(0.5f * th, &s, &c);
                const int mask = 8 >> ch;
                #pragma unroll
                for (int i = 0; i < 16; ++i) {
                    if (i & mask) continue;
                    const int j = i | mask;
                    float ar = sr[i], ai = si[i], br = sr[j], bi = si[j];
                    sr[i] = c * ar - s * br;  si[i] = c * ai - s * bi;
                    sr[j] = s * ar + c * br;  si[j] = s * ai + c * bi;
                }
            }
            // ---- weight unitaries (fused Rz*Ry*Rx) on each qubit ----
            #pragma unroll
            for (int q = 0; q < IN_CH; ++q) {
                const float* u = &sU[(pos * IN_CH + q) * 8];
                const float u00r = u[0], u00i = u[1], u01r = u[2], u01i = u[3];
                const float u10r = u[4], u10i = u[5], u11r = u[6], u11i = u[7];
                const int mask = 8 >> q;
                #pragma unroll
                for (int i = 0; i < 16; ++i) {
                    if (i & mask) continue;
                    const int j = i | mask;
                    float ar = sr[i], ai = si[i], br = sr[j], bi = si[j];
                    sr[i] = u00r * ar - u00i * ai + u01r * br - u01i * bi;
                    si[i] = u00r * ai + u00i * ar + u01r * bi + u01i * br;
                    sr[j] = u10r * ar - u10i * ai + u11r * br - u11i * bi;
                    si[j] = u10r * ai + u10i * ar + u11r * bi + u11i * br;
                }
            }
            // ---- CX ring: (0→1),(1→2),(2→3),(3→0) — pure register swaps ----
            #pragma unroll
            for (int e = 0; e < 4; ++e) {
                const int cmask = 8 >> e;
                const int tmask = 8 >> ((e + 1) & 3);
                #pragma unroll
                for (int i = 0; i < 16; ++i) {
                    if ((i & cmask) && !(i & tmask)) {
                        const int j = i | tmask;
                        float tr = sr[i]; sr[i] = sr[j]; sr[j] = tr;
                        float ti = si[i]; si[i] = si[j]; si[j] = ti;
                    }
                }
            }
        }
    }

    // ---- probabilities and <Z_q> ----
    float p2[16];
    #pragma unroll
    for (int i = 0; i < 16; ++i) p2[i] = sr[i] * sr[i] + si[i] * si[i];

    float* ob = out + ((size_t)(b * (NUM_KERNELS * IN_CH) + kidx * IN_CH) * OH + oh) * OW + ow;
    #pragma unroll
    for (int q = 0; q < IN_CH; ++q) {
        const int mask = 8 >> q;
        float e = 0.0f;
        #pragma unroll
        for (int i = 0; i < 16; ++i) e += (i & mask) ? -p2[i] : p2[i];
        ob[q * (OH * OW)] = e;
    }
}

extern "C" void kernel_launch(void* const* d_in, const int* in_sizes, int n_in,
                              void* d_out, int out_size, void* d_ws, size_t ws_size,
                              hipStream_t stream) {
    const float* x = (const float*)d_in[0];
    const float* w = (const float*)d_in[1];
    float* out = (float*)d_out;
    float* U   = (float*)d_ws;   // 2*288 floats = 2304 B of scratch

    hipLaunchKernelGGL(qk_precompute, dim3(1), dim3(128), 0, stream, w, U);
    dim3 grid((NPATCH + 255) / 256, NUM_KERNELS);
    hipLaunchKernelGGL(qk_main, grid, dim3(256), 0, stream, x, U, out);
}

// Round 4
// 74.794 us; speedup vs baseline: 1.0389x; 1.0389x over previous
//
#include <hip/hip_runtime.h>
#include <math.h>

#define IN_CH 4
#define KSZ 3
#define NUM_KERNELS 2
#define NPOS 9          // KSZ*KSZ
#define HH 64
#define WW 64
#define BB 16
#define OH 62
#define OW 62
#define NPATCH (BB*OH*OW)   // 61504 (= 961 * 64 exactly)
#define NU (NPOS*IN_CH)     // 36 unitaries per kernel
#define UFLOATS (NU*8)      // 288 floats per kernel
#define BLK 64

// ---------------------------------------------------------------------------
// Precompute the fused per-(kernel,pos,qubit) unitary  U = Rz(t2)*Ry(t1)*Rx(t0)
// 72 threads total. Written to workspace as [k][pos][q][8] floats.
// ---------------------------------------------------------------------------
__global__ void qk_precompute(const float* __restrict__ w, float* __restrict__ U) {
    int t = blockIdx.x * blockDim.x + threadIdx.x;
    if (t >= NUM_KERNELS * NU) return;
    int k   = t / NU;
    int rem = t % NU;          // pos*IN_CH + q
    const float* wp = w + k * (NU * 3) + rem * 3;   // w.reshape(NPOS,1,IN_CH,3)
    float hx = 0.5f * wp[0], hy = 0.5f * wp[1], hz = 0.5f * wp[2];
    float cx = cosf(hx), sx = sinf(hx);
    float cy = cosf(hy), sy = sinf(hy);
    float cz = cosf(hz), sz = sinf(hz);
    // M = Ry * Rx
    float m00r =  cy * cx, m00i =  sy * sx;
    float m01r = -sy * cx, m01i = -cy * sx;
    float m10r =  sy * cx, m10i = -cy * sx;
    float m11r =  cy * cx, m11i = -sy * sx;
    // U = Rz * M
    float* o = U + t * 8;
    o[0] = cz * m00r + sz * m00i;  o[1] = cz * m00i - sz * m00r;
    o[2] = cz * m01r + sz * m01i;  o[3] = cz * m01i - sz * m01r;
    o[4] = cz * m10r - sz * m10i;  o[5] = cz * m10i + sz * m10r;
    o[6] = cz * m11r - sz * m11i;  o[7] = cz * m11i + sz * m11r;
}

// ---------------------------------------------------------------------------
// Main kernel: one thread per (patch, kernel). State = 16 complex amplitudes
// in registers (qubit q bit = 8>>q). Per (pos,q) the data-RY is fused into
// the weight unitary:  F = U_w * RY(theta)  — 16 ops build + 128 ops apply
// vs 64 + 128 unfused (-25% per-pos math).
// ---------------------------------------------------------------------------
__global__ __launch_bounds__(BLK) void qk_main(const float* __restrict__ x,
                                               const float* __restrict__ Uglob,
                                               float* __restrict__ out) {
    __shared__ float sU[UFLOATS];
    const int kidx = blockIdx.y;
    const int tid  = threadIdx.x;
    for (int t = tid; t < UFLOATS; t += BLK) sU[t] = Uglob[kidx * UFLOATS + t];
    __syncthreads();

    int p = blockIdx.x * BLK + tid;
    if (p >= NPATCH) return;
    int b   = p / (OH * OW);
    int rem = p - b * (OH * OW);
    int oh  = rem / OW;
    int ow  = rem - oh * OW;
    const float* xb = x + b * (IN_CH * HH * WW) + oh * WW + ow;

    // ---- preload all 36 patch values into registers (latency paid once) ----
    float xv[NPOS * IN_CH];
    #pragma unroll
    for (int ch = 0; ch < IN_CH; ++ch)
        #pragma unroll
        for (int kh = 0; kh < KSZ; ++kh)
            #pragma unroll
            for (int kw = 0; kw < KSZ; ++kw)
                xv[(kh * KSZ + kw) * IN_CH + ch] = xb[ch * (HH * WW) + kh * WW + kw];

    float sr[16], si[16];
    #pragma unroll
    for (int i = 0; i < 16; ++i) { sr[i] = 0.25f; si[i] = 0.0f; }  // H^⊗4 |0>

    #pragma unroll
    for (int pos = 0; pos < NPOS; ++pos) {
        // ---- fused per-qubit gate F = U_w(pos,q) * RY(x_angle) ----
        #pragma unroll
        for (int q = 0; q < IN_CH; ++q) {
            float s, c;
            __sincosf(0.5f * xv[pos * IN_CH + q], &s, &c);
            const float* u = &sU[(pos * IN_CH + q) * 8];
            const float u00r = u[0], u00i = u[1], u01r = u[2], u01i = u[3];
            const float u10r = u[4], u10i = u[5], u11r = u[6], u11i = u[7];
            // F[:,0] = c*U[:,0] + s*U[:,1] ; F[:,1] = c*U[:,1] - s*U[:,0]
            const float f00r = c * u00r + s * u01r, f00i = c * u00i + s * u01i;
            const float f10r = c * u10r + s * u11r, f10i = c * u10i + s * u11i;
            const float f01r = c * u01r - s * u00r, f01i = c * u01i - s * u00i;
            const float f11r = c * u11r - s * u10r, f11i = c * u11i - s * u10i;
            const int mask = 8 >> q;
            #pragma unroll
            for (int i = 0; i < 16; ++i) {
                if (i & mask) continue;
                const int j = i | mask;
                float ar = sr[i], ai = si[i], br = sr[j], bi = si[j];
                sr[i] = f00r * ar - f00i * ai + f01r * br - f01i * bi;
                si[i] = f00r * ai + f00i * ar + f01r * bi + f01i * br;
                sr[j] = f10r * ar - f10i * ai + f11r * br - f11i * bi;
                si[j] = f10r * ai + f10i * ar + f11r * bi + f11i * br;
            }
        }
        // ---- CX ring: (0→1),(1→2),(2→3),(3→0) — register renames ----
        #pragma unroll
        for (int e = 0; e < 4; ++e) {
            const int cmask = 8 >> e;
            const int tmask = 8 >> ((e + 1) & 3);
            #pragma unroll
            for (int i = 0; i < 16; ++i) {
                if ((i & cmask) && !(i & tmask)) {
                    const int j = i | tmask;
                    float tr = sr[i]; sr[i] = sr[j]; sr[j] = tr;
                    float ti = si[i]; si[i] = si[j]; si[j] = ti;
                }
            }
        }
    }

    // ---- probabilities and <Z_q> ----
    float p2[16];
    #pragma unroll
    for (int i = 0; i < 16; ++i) p2[i] = sr[i] * sr[i] + si[i] * si[i];

    float* ob = out + ((size_t)(b * (NUM_KERNELS * IN_CH) + kidx * IN_CH) * OH + oh) * OW + ow;
    #pragma unroll
    for (int q = 0; q < IN_CH; ++q) {
        const int mask = 8 >> q;
        float e = 0.0f;
        #pragma unroll
        for (int i = 0; i < 16; ++i) e += (i & mask) ? -p2[i] : p2[i];
        ob[q * (OH * OW)] = e;
    }
}

extern "C" void kernel_launch(void* const* d_in, const int* in_sizes, int n_in,
                              void* d_out, int out_size, void* d_ws, size_t ws_size,
                              hipStream_t stream) {
    const float* x = (const float*)d_in[0];
    const float* w = (const float*)d_in[1];
    float* out = (float*)d_out;
    float* U   = (float*)d_ws;   // 2*288 floats = 2304 B of scratch

    hipLaunchKernelGGL(qk_precompute, dim3(1), dim3(128), 0, stream, w, U);
    dim3 grid((NPATCH + BLK - 1) / BLK, NUM_KERNELS);   // 961 x 2, 1 wave/wg
    hipLaunchKernelGGL(qk_main, grid, dim3(BLK), 0, stream, x, U, out);
}